// Round 1
// baseline (1117.647 us; speedup 1.0000x reference)
//
#include <hip/hip_runtime.h>
#include <math.h>

#define S 1024
#define DM 512
#define H 8
#define HD 64
#define NH 8          // n_hashes
#define NB 16         // n_buckets
#define N 8192        // B*H*S
#define SCALE 0.125f  // 1/sqrt(64)

// ---------------- K1: projection  out[n=h*S+s][d] = (x @ w + b)[s][h*64+d]
__global__ void proj_kernel(const float* __restrict__ x,
                            const float* __restrict__ w,
                            const float* __restrict__ b,
                            float* __restrict__ out) {
  int s = blockIdx.x;
  int d = threadIdx.x;      // 0..511
  __shared__ float xs[DM];
  xs[d] = x[s * DM + d];
  __syncthreads();
  float acc = b[d];
  for (int k = 0; k < DM; ++k)
    acc = fmaf(xs[k], w[k * DM + d], acc);
  int h = d >> 6, dd = d & 63;
  out[(h * S + s) * HD + dd] = acc;
}

// ---------------- K2: LSH buckets + histogram
__global__ void bucket_kernel(const float* __restrict__ qkf,
                              const float* __restrict__ rot,
                              int* __restrict__ buckets,
                              int* __restrict__ counts) {
  int g = blockIdx.x * blockDim.x + threadIdx.x;  // 0..65535
  int n = g & (N - 1);
  int r = g >> 13;
  int h = n >> 10;
  const float* q = qkf + n * HD;
  const float* R = rot + ((r * H + h) * HD) * 8;  // [d][c]
  float v[8];
#pragma unroll
  for (int c = 0; c < 8; ++c) v[c] = 0.f;
  for (int d = 0; d < HD; ++d) {
    float qd = q[d];
#pragma unroll
    for (int c = 0; c < 8; ++c)
      v[c] = fmaf(qd, R[d * 8 + c], v[c]);
  }
  // argmax over concat([v, -v]) — first occurrence wins (strict >)
  float best = v[0];
  int bi = 0;
#pragma unroll
  for (int c = 1; c < 16; ++c) {
    float val = (c < 8) ? v[c] : -v[c - 8];
    if (val > best) { best = val; bi = c; }
  }
  buckets[r * N + n] = bi;
  atomicAdd(&counts[r * NB + bi], 1);
}

// ---------------- K3: tiny exclusive scan (128 entries)
__global__ void scan_kernel(const int* __restrict__ counts,
                            int* __restrict__ offsets,
                            int* __restrict__ cursor) {
  int t = threadIdx.x;  // 0..127
  int r = t >> 4, b = t & 15;
  int off = r * N;
  for (int i = 0; i < b; ++i) off += counts[r * NB + i];
  offsets[t] = off;
  cursor[t] = off;
}

// ---------------- K4: scatter rows into bucket-sorted order
__global__ void scatter_kernel(const int* __restrict__ buckets,
                               int* __restrict__ cursor,
                               int* __restrict__ perm) {
  int g = blockIdx.x * blockDim.x + threadIdx.x;
  int n = g & (N - 1);
  int r = g >> 13;
  int b = buckets[r * N + n];
  int pos = atomicAdd(&cursor[r * NB + b], 1);
  perm[pos] = n;
}

// ---------------- K5: per-(round,bucket) dense attention, online softmax
#define CHUNKS 4
__global__ __launch_bounds__(256) void attn_kernel(
    const float* __restrict__ qkf, const float* __restrict__ vf,
    const int* __restrict__ perm, const int* __restrict__ offsets,
    const int* __restrict__ counts, float* __restrict__ accum) {
  int r = blockIdx.x >> 6;
  int b = (blockIdx.x >> 2) & 15;
  int chunk = blockIdx.x & 3;
  int start = offsets[r * NB + b];
  int cnt = counts[r * NB + b];
  if (cnt == 0) return;

  __shared__ float qkj[64 * HD];
  __shared__ float vj[64 * HD];
  int tid = threadIdx.x;

  for (int rc = chunk * 256; rc < cnt; rc += CHUNKS * 256) {
    int row = rc + tid;
    bool valid = row < cnt;
    int i = valid ? perm[start + row] : 0;
    float qi[HD], acc[HD];
    float m = -INFINITY, l = 0.f;
    if (valid) {
      const float* qp = qkf + i * HD;
#pragma unroll
      for (int d = 0; d < HD; ++d) { qi[d] = qp[d]; acc[d] = 0.f; }
    }
    for (int jt = 0; jt < cnt; jt += 64) {
      int nj = min(64, cnt - jt);
      __syncthreads();
      for (int e = tid; e < nj * HD; e += 256) {
        int jj = e >> 6, d = e & 63;
        int j = perm[start + jt + jj];
        qkj[e] = qkf[j * HD + d];
        vj[e]  = vf[j * HD + d];
      }
      __syncthreads();
      if (valid) {
        for (int jj = 0; jj < nj; ++jj) {
          float sdot = 0.f;
#pragma unroll
          for (int d = 0; d < HD; ++d)
            sdot = fmaf(qi[d], qkj[jj * HD + d], sdot);
          sdot *= SCALE;
          float nm = fmaxf(m, sdot);
          float corr = __expf(m - nm);   // exp(-inf)=0 handles first iter
          float p = __expf(sdot - nm);
          l = l * corr + p;
#pragma unroll
          for (int d = 0; d < HD; ++d)
            acc[d] = fmaf(acc[d], corr, p * vj[jj * HD + d]);
          m = nm;
        }
      }
    }
    if (valid) {
      float inv = 1.f / l;
#pragma unroll
      for (int d = 0; d < HD; ++d)
        atomicAdd(&accum[i * HD + d], acc[d] * inv);
    }
  }
}

// ---------------- K6: output projection  out[s][:] = (accum/8) @ w_o + b_o
__global__ void outproj_kernel(const float* __restrict__ accum,
                               const float* __restrict__ w_o,
                               const float* __restrict__ b_o,
                               float* __restrict__ out) {
  int s = blockIdx.x;
  int d = threadIdx.x;  // 0..511 (also plays role of k in the gather)
  __shared__ float as[DM];
  int h = d >> 6, dd = d & 63;
  as[d] = accum[(h * S + s) * HD + dd];
  __syncthreads();
  float acc = 0.f;
  for (int k = 0; k < DM; ++k)
    acc = fmaf(as[k], w_o[k * DM + d], acc);
  out[s * DM + d] = b_o[d] + acc * 0.125f;
}

extern "C" void kernel_launch(void* const* d_in, const int* in_sizes, int n_in,
                              void* d_out, int out_size, void* d_ws, size_t ws_size,
                              hipStream_t stream) {
  const float* x    = (const float*)d_in[0];
  const float* w_qk = (const float*)d_in[1];
  const float* b_qk = (const float*)d_in[2];
  const float* w_v  = (const float*)d_in[3];
  const float* b_v  = (const float*)d_in[4];
  const float* w_o  = (const float*)d_in[5];
  const float* b_o  = (const float*)d_in[6];
  const float* rot  = (const float*)d_in[7];
  float* out = (float*)d_out;

  char* ws = (char*)d_ws;
  float* qkf   = (float*)(ws);                        // 2 MB
  float* vf    = (float*)(ws + 2u * 1024 * 1024);     // 2 MB
  float* accum = (float*)(ws + 4u * 1024 * 1024);     // 2 MB
  int* buckets = (int*)(ws + 6u * 1024 * 1024);       // 256 KB
  int* perm    = (int*)(ws + 6u * 1024 * 1024 + 256u * 1024);  // 256 KB
  int* counts  = (int*)(ws + 6u * 1024 * 1024 + 512u * 1024);  // 512 B
  int* offsets = counts + 128;
  int* cursor  = offsets + 128;

  hipMemsetAsync(counts, 0, 128 * sizeof(int), stream);
  hipMemsetAsync(accum, 0, (size_t)N * HD * sizeof(float), stream);

  proj_kernel<<<S, DM, 0, stream>>>(x, w_qk, b_qk, qkf);
  proj_kernel<<<S, DM, 0, stream>>>(x, w_v, b_v, vf);
  bucket_kernel<<<(NH * N) / 256, 256, 0, stream>>>(qkf, rot, buckets, counts);
  scan_kernel<<<1, 128, 0, stream>>>(counts, offsets, cursor);
  scatter_kernel<<<(NH * N) / 256, 256, 0, stream>>>(buckets, cursor, perm);
  attn_kernel<<<NH * NB * CHUNKS, 256, 0, stream>>>(qkf, vf, perm, offsets, counts, accum);
  outproj_kernel<<<S, DM, 0, stream>>>(accum, w_o, b_o, out);
}